// Round 4
// baseline (562.728 us; speedup 1.0000x reference)
//
#include <hip/hip_runtime.h>

typedef unsigned short u16;
typedef __attribute__((ext_vector_type(8))) short bf16x8;
typedef __attribute__((ext_vector_type(4))) float f32x4;

// B=4, C=Cin=256, H=W=128.
// Activations live in a "staging-ready" global layout:
//   [b][h][half(ci>>7)][w][256B], each 256B half-row internally XOR-swizzled
//   by key ((w+1)&7)<<4 so a LINEAR global_load_lds lands bank-conflict-free
//   for ds_read_b128 MFMA fragments (LDS row = wp = w+1).
// plane(b,h) = 65536 B, batch = 8,388,608 B, tensor = 32 MB.

__device__ __forceinline__ u16 f2bf(float f) {
  unsigned u = __float_as_uint(f);
  unsigned r = u + 0x7fffu + ((u >> 16) & 1u);
  return (u16)(r >> 16);
}

__device__ __forceinline__ void gll16(const char* g, char* l) {
  __builtin_amdgcn_global_load_lds((const __attribute__((address_space(1))) void*)g,
                                   (__attribute__((address_space(3))) void*)l, 16, 0, 0);
}

// ---------------- BN prep: s = g*rsqrt(v+eps), t = b - m*s ----------------
__global__ void bn_prep_kernel(const float* __restrict__ g, const float* __restrict__ b,
                               const float* __restrict__ m, const float* __restrict__ v,
                               float* __restrict__ st) {
  int c = threadIdx.x;
  float s = g[c] * rsqrtf(v[c] + 1e-5f);
  st[c] = s;
  st[256 + c] = b[c] - m[c] * s;
}

// fold c1 BN into merge: t_p += t_c1 ; ratio = s_c1/s_p stored in c1's s-slot
__global__ void bn_fix_kernel(float* __restrict__ st) {
  int c = threadIdx.x;
  st[2 * 512 + 256 + c] += st[3 * 512 + 256 + c];
  st[3 * 512 + c] = st[3 * 512 + c] / st[2 * 512 + c];
}

// ---------------- weight prep: per-step 16KB blocks in exact LDS image ----------------
__global__ void wprep3_kernel(const float* __restrict__ w, u16* __restrict__ dst) {
  int idx = blockIdx.x * 256 + threadIdx.x;        // 589,824 u16
  int blk = idx >> 13, iu = idx & 8191;
  int co = iu >> 5, w32 = iu & 31, slot = w32 >> 3, e = w32 & 7;
  int q = slot ^ ((co >> 1) & 3);
  int kc = blk & 3, t = blk >> 2;
  int dwi = t % 3, t2 = t / 3, d = t2 % 3, half = t2 / 3;
  int s = d * 3 + dwi;
  int ci = half * 128 + kc * 32 + q * 8 + e;
  dst[idx] = f2bf(w[(co * 256 + ci) * 9 + s]);
}

__global__ void wprep1_kernel(const float* __restrict__ w, u16* __restrict__ dst,
                              const float* __restrict__ ratio) {
  int idx = blockIdx.x * 256 + threadIdx.x;        // 65,536 u16, blk = half*4+kc
  int blk = idx >> 13, iu = idx & 8191;
  int co = iu >> 5, w32 = iu & 31, slot = w32 >> 3, e = w32 & 7;
  int q = slot ^ ((co >> 1) & 3);
  int kc = blk & 3, half = blk >> 2;
  int ci = half * 128 + kc * 32 + q * 8 + e;
  dst[idx] = f2bf(w[co * 256 + ci] * ratio[co]);
}

// ---------------- NCHW fp32 -> staging layout bf16 ----------------
__global__ __launch_bounds__(256) void nchw_to_nhwc_kernel(const float* __restrict__ x,
                                                           char* __restrict__ xb) {
  __shared__ __align__(16) u16 tl[128 * 130];
  int bh = blockIdx.x; int b = bh >> 7, h = bh & 127;
  int t = threadIdx.x;
  for (int half = 0; half < 2; ++half) {
    __syncthreads();
    for (int i = 0; i < 64; ++i) {
      int cil = i * 2 + (t >> 7);
      int ci = half * 128 + cil;
      int w = t & 127;
      tl[w * 130 + cil] = f2bf(x[(size_t)((b * 256 + ci) * 128 + h) * 128 + w]);
    }
    __syncthreads();
    char* plane = xb + (size_t)(b * 128 + h) * 65536 + half * 32768;
    for (int i = 0; i < 32; ++i) {
      int w = i * 4 + (t >> 6);
      int c2 = (t & 63) * 2;   // u16 index within half
      unsigned v = *(const unsigned*)&tl[w * 130 + c2];
      *(unsigned*)(plane + w * 256 + ((c2 * 2) ^ (((w + 1) & 7) << 4))) = v;
    }
  }
}

// ---- staging helpers: plain free functions, NO access to acc ----
__device__ __forceinline__ void stage_a(const char* wA1, const char* wA2, int step,
                                        char* ldsA0, int buf, int wv, int lane) {
  const char* src = (step < 72) ? (wA1 + (size_t)step * 16384)
                                : (wA2 + (size_t)(step - 72) * 16384);
  char* dst = ldsA0 + buf * 16384 + wv * 1024;
  const char* g = src + wv * 1024 + lane * 16;
  gll16(g, dst);
  gll16(g + 8192, dst + 8192);
}

__device__ __forceinline__ void stage_b(const char* plane, char* ldsB, int t, int wv, int lane) {
  if (plane) {
    char* dst = ldsB + 256 + wv * 1024;          // rows wp 1..128
    const char* g = plane + wv * 1024 + lane * 16;
#pragma unroll
    for (int r = 0; r < 4; ++r) gll16(g + r * 8192, dst + r * 8192);
  } else {
    int4 z = {0, 0, 0, 0};
#pragma unroll
    for (int r = 0; r < 4; ++r) *(int4*)(ldsB + r * 8192 + t * 16) = z;
    if (t < 32) *(int4*)(ldsB + 32768 + t * 16) = z;
  }
}

// ---------------- shared 8-wave conv pipeline (counted-vmcnt 2-phase, T4+T5) -------------
// Block: 512 thr (8 waves), output [256 co][128 w] at fixed (b,h).
// LDS: B rows wp 0..129 (33,280B) + A double-buffer 2x16,384B = 66,048B -> 2 blocks/CU.
// Per step (STRAIGHT-LINE, no lambdas so acc never escapes to scratch):
//   stageA(i+1) -> s_waitcnt vmcnt(2) lgkmcnt(0) -> s_barrier -> sched_barrier ->
//   ds_read frags -> setprio(1) 16 MFMA setprio(0) -> s_barrier (buffer release).
#define CONV_STEP(WP_ADD, KC)                                                              \
  {                                                                                        \
    if (i + 1 < nsteps) {                                                                  \
      stage_a(wA1, wA2, i + 1, ldsA0, cur ^ 1, wv, lane);                                  \
      asm volatile("s_waitcnt vmcnt(2) lgkmcnt(0)" ::: "memory");                          \
    } else {                                                                               \
      asm volatile("s_waitcnt vmcnt(0) lgkmcnt(0)" ::: "memory");                          \
    }                                                                                      \
    __builtin_amdgcn_s_barrier();                                                          \
    __builtin_amdgcn_sched_barrier(0);                                                     \
    bf16x8 af[4], bf[4];                                                                   \
    const char* lA = ldsA0 + cur * 16384;                                                  \
    _Pragma("unroll")                                                                      \
    for (int f = 0; f < 4; ++f) af[f] = *(const bf16x8*)(lA + aOff[f]);                    \
    _Pragma("unroll")                                                                      \
    for (int f = 0; f < 4; ++f) {                                                          \
      int wp = wpb[f] + (WP_ADD);                                                          \
      bf[f] = *(const bf16x8*)(ldsB + wp * 256 + (((KC)*64 + q * 16) ^ ((wp & 7) << 4)));  \
    }                                                                                      \
    __builtin_amdgcn_s_setprio(1);                                                         \
    _Pragma("unroll")                                                                      \
    for (int fm = 0; fm < 4; ++fm)                                                         \
      _Pragma("unroll")                                                                    \
      for (int fn = 0; fn < 4; ++fn)                                                       \
        acc[fm][fn] =                                                                      \
            __builtin_amdgcn_mfma_f32_16x16x32_bf16(af[fm], bf[fn], acc[fm][fn], 0, 0, 0); \
    __builtin_amdgcn_s_setprio(0);                                                         \
    __builtin_amdgcn_s_barrier();                                                          \
    cur ^= 1;                                                                              \
    ++i;                                                                                   \
  }

__device__ __forceinline__ void conv_pipeline(const char* inB1, const char* inB2,
                                              const char* wA1, const char* wA2,
                                              int h, int nsteps, char* lds,
                                              f32x4 (&acc)[4][4]) {
  const int t = threadIdx.x;
  const int wv = t >> 6, lane = t & 63;
  const int lane15 = lane & 15, q = lane >> 4;
  const int coq = wv >> 1, wh = wv & 1;
  char* ldsB = lds;
  char* ldsA0 = lds + 33280;

  int aOff[4];
#pragma unroll
  for (int f = 0; f < 4; ++f) {
    int ra = coq * 64 + f * 16 + lane15;
    aOff[f] = ra * 64 + ((q ^ ((ra >> 1) & 3)) << 4);
  }
  int wpb[4];
#pragma unroll
  for (int f = 0; f < 4; ++f) wpb[f] = wh * 64 + f * 16 + lane15;

  // zero pad rows 0 (w=-1) and 129 (w=128) ONCE; stage_b only writes rows 1..128.
  {
    int4 z = {0, 0, 0, 0};
    if (t < 16) *(int4*)(ldsB + t * 16) = z;
    else if (t < 32) *(int4*)(ldsB + 33024 + (t - 16) * 16) = z;
  }

  int cur = 0, i = 0;
  for (int outer = 0; outer < 6; ++outer) {
    const int half = (outer >= 3) ? 1 : 0;
    const int d = outer - half * 3;
    const int hs = h + d - 1;
    const char* plane = (hs >= 0 && hs < 128)
                            ? inB1 + (size_t)hs * 65536 + (size_t)half * 32768
                            : nullptr;
    stage_b(plane, ldsB, t, wv, lane);
    if (outer == 0) stage_a(wA1, wA2, 0, ldsA0, 0, wv, lane);
#pragma unroll
    for (int dwi = 0; dwi < 3; ++dwi)
#pragma unroll
      for (int kc = 0; kc < 4; ++kc) CONV_STEP(dwi, kc)
  }
  if (nsteps > 72) {   // fused 1x1 (c1) segment: rows h, dw=0
    for (int half2 = 0; half2 < 2; ++half2) {
      stage_b(inB2 + (size_t)h * 65536 + (size_t)half2 * 32768, ldsB, t, wv, lane);
#pragma unroll
      for (int kc = 0; kc < 4; ++kc) CONV_STEP(1, kc)
    }
  }
}

__device__ __forceinline__ void zero_acc(f32x4 (&acc)[4][4]) {
  f32x4 z = {0.f, 0.f, 0.f, 0.f};
#pragma unroll
  for (int i = 0; i < 4; ++i)
#pragma unroll
    for (int j = 0; j < 4; ++j) acc[i][j] = z;
}

// BN+ReLU, store to staging layout (8B = 4 co per lane)
__device__ __forceinline__ void store_pad_relu(f32x4 (&acc)[4][4], const float* __restrict__ st,
                                               int b, int h, char* __restrict__ out) {
  const int t = threadIdx.x, lane = t & 63, wv = t >> 6;
  const int lane15 = lane & 15, q = lane >> 4, coq = wv >> 1, wh = wv & 1;
  char* plane = out + (size_t)(b * 128 + h) * 65536;
#pragma unroll
  for (int fm = 0; fm < 4; ++fm) {
    int co = coq * 64 + fm * 16 + q * 4;
    float ss[4], tt[4];
#pragma unroll
    for (int r = 0; r < 4; ++r) { ss[r] = st[co + r]; tt[r] = st[256 + co + r]; }
#pragma unroll
    for (int fn = 0; fn < 4; ++fn) {
      int w = wh * 64 + fn * 16 + lane15;
      short4 o;
      o.x = (short)f2bf(fmaxf(acc[fm][fn][0] * ss[0] + tt[0], 0.f));
      o.y = (short)f2bf(fmaxf(acc[fm][fn][1] * ss[1] + tt[1], 0.f));
      o.z = (short)f2bf(fmaxf(acc[fm][fn][2] * ss[2] + tt[2], 0.f));
      o.w = (short)f2bf(fmaxf(acc[fm][fn][3] * ss[3] + tt[3], 0.f));
      *(short4*)(plane + (co >> 7) * 32768 + w * 256 + (((co & 127) * 2) ^ (((w + 1) & 7) << 4))) = o;
    }
  }
}

// ---------------- up conv: BN+ReLU then fused row-max over W ----------------
__global__ __launch_bounds__(512, 4) void conv_up_kernel(const char* __restrict__ xb,
                                                         const char* __restrict__ wp,
                                                         const float* __restrict__ st,
                                                         float* __restrict__ rmax) {
  __shared__ __align__(16) char lds[66048];
  int swz = (blockIdx.x & 7) * 64 + (blockIdx.x >> 3);
  int b = swz >> 7, h = swz & 127;
  f32x4 acc[4][4];
  zero_acc(acc);
  conv_pipeline(xb + (size_t)b * 8388608, nullptr, wp, nullptr, h, 72, lds, acc);

  const int t = threadIdx.x, lane = t & 63, wv = t >> 6;
  const int lane15 = lane & 15, q = lane >> 4, coq = wv >> 1, wh = wv & 1;
  float* rlds = (float*)lds;
  __syncthreads();
#pragma unroll
  for (int fm = 0; fm < 4; ++fm) {
    int co = coq * 64 + fm * 16 + q * 4;
#pragma unroll
    for (int r = 0; r < 4; ++r) {
      float ss = st[co + r], tt = st[256 + co + r];
      float v = 0.f;   // ReLU floor
#pragma unroll
      for (int fn = 0; fn < 4; ++fn) v = fmaxf(v, acc[fm][fn][r] * ss + tt);
      v = fmaxf(v, __shfl_xor(v, 1));
      v = fmaxf(v, __shfl_xor(v, 2));
      v = fmaxf(v, __shfl_xor(v, 4));
      v = fmaxf(v, __shfl_xor(v, 8));
      if (lane15 == 0) rlds[wh * 256 + co + r] = v;
    }
  }
  __syncthreads();
  if (t < 256) rmax[(size_t)(b * 128 + h) * 256 + t] = fmaxf(rlds[t], rlds[256 + t]);
}

// ---------------- down conv ----------------
__global__ __launch_bounds__(512, 4) void conv_down_kernel(const char* __restrict__ xb,
                                                           const char* __restrict__ wp,
                                                           const float* __restrict__ st,
                                                           char* __restrict__ out) {
  __shared__ __align__(16) char lds[66048];
  int swz = (blockIdx.x & 7) * 64 + (blockIdx.x >> 3);
  int b = swz >> 7, h = swz & 127;
  f32x4 acc[4][4];
  zero_acc(acc);
  conv_pipeline(xb + (size_t)b * 8388608, nullptr, wp, nullptr, h, 72, lds, acc);
  store_pad_relu(acc, st, b, h, out);
}

// ---------------- col max over H ----------------
__global__ __launch_bounds__(256) void colmax_kernel(const char* __restrict__ dp,
                                                     float* __restrict__ cmax) {
  int bw = blockIdx.x; int b = bw >> 7, w = bw & 127;
  int c = threadIdx.x;
  size_t base = (size_t)b * 8388608 + (size_t)(c >> 7) * 32768 + w * 256 +
                (((c & 127) * 2) ^ (((w + 1) & 7) << 4));
  float m = 0.f;
  for (int h = 0; h < 128; ++h) {
    u16 raw = *(const u16*)(dp + base + (size_t)h * 65536);
    m = fmaxf(m, __uint_as_float(((unsigned)raw) << 16));
  }
  cmax[(size_t)(b * 128 + w) * 256 + c] = m;
}

// ---------------- pooled = rmax[b,h,c] + cmax[b,w,c], into staging layout ----------------
__global__ __launch_bounds__(256) void pooled_kernel(const float* __restrict__ rmax,
                                                     const float* __restrict__ cmax,
                                                     char* __restrict__ dp) {
  int bh = blockIdx.x; int b = bh >> 7, h = bh & 127;
  int c = threadIdx.x;
  float rm = rmax[(size_t)(b * 128 + h) * 256 + c];
  char* plane = dp + (size_t)(b * 128 + h) * 65536 + (c >> 7) * 32768;
  int cb = (c & 127) * 2;
  for (int w = 0; w < 128; ++w) {
    float v = rm + cmax[(size_t)(b * 128 + w) * 256 + c];
    *(u16*)(plane + w * 256 + (cb ^ (((w + 1) & 7) << 4))) = f2bf(v);
  }
}

// ---------------- merge conv (pooled 3x3) + fused c1 (1x1 on xb) ----------------
__global__ __launch_bounds__(512, 4) void conv_merge_kernel(const char* __restrict__ dp,
                                                            const char* __restrict__ xb,
                                                            const char* __restrict__ wp_p,
                                                            const char* __restrict__ wp_c1,
                                                            const float* __restrict__ st,
                                                            char* __restrict__ out) {
  __shared__ __align__(16) char lds[66048];
  int swz = (blockIdx.x & 7) * 64 + (blockIdx.x >> 3);
  int b = swz >> 7, h = swz & 127;
  f32x4 acc[4][4];
  zero_acc(acc);
  conv_pipeline(dp + (size_t)b * 8388608, xb + (size_t)b * 8388608, wp_p, wp_c1, h, 80, lds, acc);
  store_pad_relu(acc, st, b, h, out);
}

// ---------------- final conv c2: BN+ReLU, NCHW fp32 out via LDS transpose ----------------
__global__ __launch_bounds__(512, 4) void conv_c2_kernel(const char* __restrict__ relu1,
                                                         const char* __restrict__ wp,
                                                         const float* __restrict__ st,
                                                         float* __restrict__ out) {
  __shared__ __align__(16) char lds[66048];
  int swz = (blockIdx.x & 7) * 64 + (blockIdx.x >> 3);
  int b = swz >> 7, h = swz & 127;
  f32x4 acc[4][4];
  zero_acc(acc);
  conv_pipeline(relu1 + (size_t)b * 8388608, nullptr, wp, nullptr, h, 72, lds, acc);

  const int t = threadIdx.x, lane = t & 63, wv = t >> 6;
  const int lane15 = lane & 15, q = lane >> 4, coq = wv >> 1, wh = wv & 1;
  float* tl = (float*)lds;   // [16][132]
  for (int g = 0; g < 16; ++g) {
    __syncthreads();
    if (coq == (g >> 2)) {
      int fm = g & 3;
      int co = coq * 64 + fm * 16 + q * 4;
#pragma unroll
      for (int r = 0; r < 4; ++r) {
        float ss = st[co + r], tt = st[256 + co + r];
#pragma unroll
        for (int fn = 0; fn < 4; ++fn) {
          int w = wh * 64 + fn * 16 + lane15;
          tl[(q * 4 + r) * 132 + w] = fmaxf(acc[fm][fn][r] * ss + tt, 0.f);
        }
      }
    }
    __syncthreads();
    int row = t >> 5, wq = (t & 31) * 4;
    float4 vv = *(float4*)&tl[row * 132 + wq];
    *(float4*)(out + (size_t)((b * 256 + g * 16 + row) * 128 + h) * 128 + wq) = vv;
  }
}

extern "C" void kernel_launch(void* const* d_in, const int* in_sizes, int n_in,
                              void* d_out, int out_size, void* d_ws, size_t ws_size,
                              hipStream_t stream) {
  (void)in_sizes; (void)n_in; (void)out_size; (void)ws_size;
  const float* x    = (const float*)d_in[0];
  const float* w_up = (const float*)d_in[1];
  const float* w_dn = (const float*)d_in[6];
  const float* w_p  = (const float*)d_in[11];
  const float* w_c1 = (const float*)d_in[16];
  const float* w_c2 = (const float*)d_in[21];

  // ws layout (bytes) — total 106,571,776
  char* ws = (char*)d_ws;
  char* xb    = ws;                         // 33,554,432 (32MB staging layout)
  char* dp    = ws + 33554432ull;           // 33,554,432 (down, then pooled)
  char* relu1 = ws + 67108864ull;           // 33,554,432
  u16* wp_up  = (u16*)(ws + 100663296ull);  // 1,179,648
  u16* wp_dn  = (u16*)(ws + 101842944ull);  // 1,179,648
  u16* wp_p   = (u16*)(ws + 103022592ull);  // 1,179,648
  u16* wp_c2  = (u16*)(ws + 104202240ull);  // 1,179,648
  u16* wp_c1  = (u16*)(ws + 105381888ull);  // 131,072
  float* st   = (float*)(ws + 105512960ull);// 10,240
  float* rmax = (float*)(ws + 105523200ull);// 524,288
  float* cmax = (float*)(ws + 106047488ull);// 524,288

  bn_prep_kernel<<<1, 256, 0, stream>>>((const float*)d_in[2], (const float*)d_in[3],
                                        (const float*)d_in[4], (const float*)d_in[5], st);
  bn_prep_kernel<<<1, 256, 0, stream>>>((const float*)d_in[7], (const float*)d_in[8],
                                        (const float*)d_in[9], (const float*)d_in[10], st + 512);
  bn_prep_kernel<<<1, 256, 0, stream>>>((const float*)d_in[12], (const float*)d_in[13],
                                        (const float*)d_in[14], (const float*)d_in[15], st + 1024);
  bn_prep_kernel<<<1, 256, 0, stream>>>((const float*)d_in[17], (const float*)d_in[18],
                                        (const float*)d_in[19], (const float*)d_in[20], st + 1536);
  bn_prep_kernel<<<1, 256, 0, stream>>>((const float*)d_in[22], (const float*)d_in[23],
                                        (const float*)d_in[24], (const float*)d_in[25], st + 2048);
  bn_fix_kernel<<<1, 256, 0, stream>>>(st);

  wprep3_kernel<<<2304, 256, 0, stream>>>(w_up, wp_up);
  wprep3_kernel<<<2304, 256, 0, stream>>>(w_dn, wp_dn);
  wprep3_kernel<<<2304, 256, 0, stream>>>(w_p, wp_p);
  wprep3_kernel<<<2304, 256, 0, stream>>>(w_c2, wp_c2);
  wprep1_kernel<<<256, 256, 0, stream>>>(w_c1, wp_c1, st + 1536);

  nchw_to_nhwc_kernel<<<512, 256, 0, stream>>>(x, xb);

  conv_up_kernel<<<512, 512, 0, stream>>>(xb, (const char*)wp_up, st, rmax);
  conv_down_kernel<<<512, 512, 0, stream>>>(xb, (const char*)wp_dn, st + 512, dp);
  colmax_kernel<<<512, 256, 0, stream>>>(dp, cmax);
  pooled_kernel<<<512, 256, 0, stream>>>(rmax, cmax, dp);
  conv_merge_kernel<<<512, 512, 0, stream>>>(dp, xb, (const char*)wp_p, (const char*)wp_c1,
                                             st + 1024, relu1);
  conv_c2_kernel<<<512, 512, 0, stream>>>(relu1, (const char*)wp_c2, st + 2048, (float*)d_out);
}

// Round 5
// 397.607 us; speedup vs baseline: 1.4153x; 1.4153x over previous
//
#include <hip/hip_runtime.h>

typedef unsigned short u16;
typedef __attribute__((ext_vector_type(8))) short bf16x8;
typedef __attribute__((ext_vector_type(4))) float f32x4;

// B=4, C=Cin=256, H=W=128.
// Activations live in a "staging-ready" global layout:
//   [b][h][half(ci>>7)][w][256B], each 256B half-row internally XOR-swizzled
//   by key ((w+1)&7)<<4 so a LINEAR global_load_lds lands bank-conflict-free
//   for ds_read_b128 MFMA fragments (LDS row = wp = w+1).
// plane(b,h) = 65536 B, batch = 8,388,608 B, tensor = 32 MB.
//
// Conv blocks: 256 threads (4 waves), tile [128co x 128w] at fixed (b,h),
// grid (512, 2co-halves). LDS 49,664 B -> 3 blocks/CU; regs fit under the
// 168/wave cap at 3 waves/SIMD (acc 64 + frags 32 + addr ~40) -> no spill.

__device__ __forceinline__ u16 f2bf(float f) {
  unsigned u = __float_as_uint(f);
  unsigned r = u + 0x7fffu + ((u >> 16) & 1u);
  return (u16)(r >> 16);
}

__device__ __forceinline__ void gll16(const char* g, char* l) {
  __builtin_amdgcn_global_load_lds((const __attribute__((address_space(1))) void*)g,
                                   (__attribute__((address_space(3))) void*)l, 16, 0, 0);
}

// ---------------- BN prep: s = g*rsqrt(v+eps), t = b - m*s ----------------
__global__ void bn_prep_kernel(const float* __restrict__ g, const float* __restrict__ b,
                               const float* __restrict__ m, const float* __restrict__ v,
                               float* __restrict__ st) {
  int c = threadIdx.x;
  float s = g[c] * rsqrtf(v[c] + 1e-5f);
  st[c] = s;
  st[256 + c] = b[c] - m[c] * s;
}

// fold c1 BN into merge: t_p += t_c1 ; ratio = s_c1/s_p stored in c1's s-slot
__global__ void bn_fix_kernel(float* __restrict__ st) {
  int c = threadIdx.x;
  st[2 * 512 + 256 + c] += st[3 * 512 + 256 + c];
  st[3 * 512 + c] = st[3 * 512 + c] / st[2 * 512 + c];
}

// ---------------- weight prep: per-(cohalf,step) 8KB blocks in exact LDS image ---------
// Block layout: [cohalf(2)][step(72)][128 co_l rows x 64B]. Within a row, the 4
// 16B slots are XOR-swizzled by key (co_l>>1)&3. step = outer*12 + dwi*4 + kc,
// outer = half*3 + d  (half = ci>>7, d = dh+1), s = d*3 + dwi,
// ci = half*128 + kc*32 + q*8 + e with q = slot ^ key.
__global__ void wprep3_kernel(const float* __restrict__ w, u16* __restrict__ dst) {
  int idx = blockIdx.x * 256 + threadIdx.x;        // 589,824 u16
  int blk = idx >> 12, iu = idx & 4095;
  int co_l = iu >> 5, w32 = iu & 31, slot = w32 >> 3, e = w32 & 7;
  int q = slot ^ ((co_l >> 1) & 3);
  int cohalf = blk / 72, step = blk % 72;
  int outer = step / 12, rr = step % 12, dwi = rr >> 2, kc = rr & 3;
  int half = outer / 3, d = outer % 3;
  int s = d * 3 + dwi;
  int ci = half * 128 + kc * 32 + q * 8 + e;
  int co = cohalf * 128 + co_l;
  dst[idx] = f2bf(w[(co * 256 + ci) * 9 + s]);
}

// c1: [cohalf(2)][step(8 = half2*4+kc)][128 x 64B], same row swizzle.
__global__ void wprep1_kernel(const float* __restrict__ w, u16* __restrict__ dst,
                              const float* __restrict__ ratio) {
  int idx = blockIdx.x * 256 + threadIdx.x;        // 65,536 u16
  int blk = idx >> 12, iu = idx & 4095;
  int co_l = iu >> 5, w32 = iu & 31, slot = w32 >> 3, e = w32 & 7;
  int q = slot ^ ((co_l >> 1) & 3);
  int cohalf = blk >> 3, j = blk & 7;
  int half2 = j >> 2, kc = j & 3;
  int ci = half2 * 128 + kc * 32 + q * 8 + e;
  int co = cohalf * 128 + co_l;
  dst[idx] = f2bf(w[co * 256 + ci] * ratio[co]);
}

// ---------------- NCHW fp32 -> staging layout bf16 ----------------
__global__ __launch_bounds__(256) void nchw_to_nhwc_kernel(const float* __restrict__ x,
                                                           char* __restrict__ xb) {
  __shared__ __align__(16) u16 tl[128 * 130];
  int bh = blockIdx.x; int b = bh >> 7, h = bh & 127;
  int t = threadIdx.x;
  for (int half = 0; half < 2; ++half) {
    __syncthreads();
    for (int i = 0; i < 64; ++i) {
      int cil = i * 2 + (t >> 7);
      int ci = half * 128 + cil;
      int w = t & 127;
      tl[w * 130 + cil] = f2bf(x[(size_t)((b * 256 + ci) * 128 + h) * 128 + w]);
    }
    __syncthreads();
    char* plane = xb + (size_t)(b * 128 + h) * 65536 + half * 32768;
    for (int i = 0; i < 32; ++i) {
      int w = i * 4 + (t >> 6);
      int c2 = (t & 63) * 2;   // u16 index within half
      unsigned v = *(const unsigned*)&tl[w * 130 + c2];
      *(unsigned*)(plane + w * 256 + ((c2 * 2) ^ (((w + 1) & 7) << 4))) = v;
    }
  }
}

// ---- staging helpers (256-thread block): plain free functions ----
__device__ __forceinline__ void stage_a(const char* wA1, const char* wA2, int step,
                                        char* ldsA0, int buf, int t) {
  const char* src = (step < 72) ? (wA1 + (size_t)step * 8192)
                                : (wA2 + (size_t)(step - 72) * 8192);
  char* dst = ldsA0 + buf * 8192 + t * 16;
  const char* g = src + t * 16;
  gll16(g, dst);
  gll16(g + 4096, dst + 4096);
}

__device__ __forceinline__ void stage_b(const char* plane, char* ldsB, int t) {
  if (plane) {
    char* dst = ldsB + 256 + t * 16;             // rows wp 1..128
    const char* g = plane + t * 16;
#pragma unroll
    for (int r = 0; r < 8; ++r) gll16(g + r * 4096, dst + r * 4096);
  } else {
    int4 z = {0, 0, 0, 0};
#pragma unroll
    for (int r = 0; r < 8; ++r) *(int4*)(ldsB + 256 + r * 4096 + t * 16) = z;
  }
}

// ---------------- shared 4-wave conv pipeline ----------------
// LDS: B rows wp 0..129 (33,280B) + A double-buffer 2x8,192B = 49,664B.
// Per step (r2-proven): stageA(i+1) -> ds_read frags(cur) -> 16 MFMA -> __syncthreads.
__device__ __forceinline__ void conv_pipeline(const char* inB1, const char* inB2,
                                              const char* wA1, const char* wA2,
                                              int h, int nsteps, char* lds,
                                              f32x4 (&acc)[4][4]) {
  const int t = threadIdx.x;
  const int wv = t >> 6, lane = t & 63;
  const int lane15 = lane & 15, q = lane >> 4;
  const int coq = wv >> 1, wh = wv & 1;
  char* ldsB = lds;
  char* ldsA0 = lds + 33280;

  int aOff[4];
#pragma unroll
  for (int f = 0; f < 4; ++f) {
    int ra = coq * 64 + f * 16 + lane15;          // co_l in [0,128)
    aOff[f] = ra * 64 + ((q ^ ((ra >> 1) & 3)) << 4);
  }
  int wpb[4];
#pragma unroll
  for (int f = 0; f < 4; ++f) wpb[f] = wh * 64 + f * 16 + lane15;

  // zero pad rows 0 (w=-1) and 129 (w=128) ONCE; stage_b only writes rows 1..128.
  {
    int4 z = {0, 0, 0, 0};
    if (t < 16) *(int4*)(ldsB + t * 16) = z;
    else if (t < 32) *(int4*)(ldsB + 33024 + (t - 16) * 16) = z;
  }

  int cur = 0, i = 0;
  for (int outer = 0; outer < 6; ++outer) {
    const int half = (outer >= 3) ? 1 : 0;
    const int d = outer - half * 3;
    const int hs = h + d - 1;
    const char* plane = (hs >= 0 && hs < 128)
                            ? inB1 + (size_t)hs * 65536 + (size_t)half * 32768
                            : nullptr;
    stage_b(plane, ldsB, t);
    if (outer == 0) stage_a(wA1, wA2, 0, ldsA0, 0, t);
    __syncthreads();
#pragma unroll
    for (int dwi = 0; dwi < 3; ++dwi)
#pragma unroll
      for (int kc = 0; kc < 4; ++kc) {
        if (i + 1 < nsteps) stage_a(wA1, wA2, i + 1, ldsA0, cur ^ 1, t);
        bf16x8 af[4], bf[4];
        const char* lA = ldsA0 + cur * 8192;
#pragma unroll
        for (int f = 0; f < 4; ++f) af[f] = *(const bf16x8*)(lA + aOff[f]);
#pragma unroll
        for (int f = 0; f < 4; ++f) {
          int wp = wpb[f] + dwi;
          bf[f] = *(const bf16x8*)(ldsB + wp * 256 + ((kc * 64 + q * 16) ^ ((wp & 7) << 4)));
        }
#pragma unroll
        for (int fm = 0; fm < 4; ++fm)
#pragma unroll
          for (int fn = 0; fn < 4; ++fn)
            acc[fm][fn] = __builtin_amdgcn_mfma_f32_16x16x32_bf16(af[fm], bf[fn], acc[fm][fn], 0, 0, 0);
        __syncthreads();
        cur ^= 1;
        ++i;
      }
  }
  if (nsteps > 72) {   // fused 1x1 (c1) segment: row h, dw=0 (wp = w+1)
    for (int half2 = 0; half2 < 2; ++half2) {
      stage_b(inB2 + (size_t)h * 65536 + (size_t)half2 * 32768, ldsB, t);
      __syncthreads();
#pragma unroll
      for (int kc = 0; kc < 4; ++kc) {
        if (i + 1 < nsteps) stage_a(wA1, wA2, i + 1, ldsA0, cur ^ 1, t);
        bf16x8 af[4], bf[4];
        const char* lA = ldsA0 + cur * 8192;
#pragma unroll
        for (int f = 0; f < 4; ++f) af[f] = *(const bf16x8*)(lA + aOff[f]);
#pragma unroll
        for (int f = 0; f < 4; ++f) {
          int wp = wpb[f] + 1;
          bf[f] = *(const bf16x8*)(ldsB + wp * 256 + ((kc * 64 + q * 16) ^ ((wp & 7) << 4)));
        }
#pragma unroll
        for (int fm = 0; fm < 4; ++fm)
#pragma unroll
          for (int fn = 0; fn < 4; ++fn)
            acc[fm][fn] = __builtin_amdgcn_mfma_f32_16x16x32_bf16(af[fm], bf[fn], acc[fm][fn], 0, 0, 0);
        __syncthreads();
        cur ^= 1;
        ++i;
      }
    }
  }
}

__device__ __forceinline__ void zero_acc(f32x4 (&acc)[4][4]) {
  f32x4 z = {0.f, 0.f, 0.f, 0.f};
#pragma unroll
  for (int i = 0; i < 4; ++i)
#pragma unroll
    for (int j = 0; j < 4; ++j) acc[i][j] = z;
}

// BN+ReLU, store to staging layout (8B = 4 co per lane); block covers co-half `cohalf`.
__device__ __forceinline__ void store_pad_relu(f32x4 (&acc)[4][4], const float* __restrict__ st,
                                               int cohalf, int b, int h, char* __restrict__ out) {
  const int t = threadIdx.x, lane = t & 63, wv = t >> 6;
  const int lane15 = lane & 15, q = lane >> 4, coq = wv >> 1, wh = wv & 1;
  char* plane = out + (size_t)(b * 128 + h) * 65536 + cohalf * 32768;
#pragma unroll
  for (int fm = 0; fm < 4; ++fm) {
    int co_l = coq * 64 + fm * 16 + q * 4;
    int co = cohalf * 128 + co_l;
    float ss[4], tt[4];
#pragma unroll
    for (int r = 0; r < 4; ++r) { ss[r] = st[co + r]; tt[r] = st[256 + co + r]; }
#pragma unroll
    for (int fn = 0; fn < 4; ++fn) {
      int w = wh * 64 + fn * 16 + lane15;
      short4 o;
      o.x = (short)f2bf(fmaxf(acc[fm][fn][0] * ss[0] + tt[0], 0.f));
      o.y = (short)f2bf(fmaxf(acc[fm][fn][1] * ss[1] + tt[1], 0.f));
      o.z = (short)f2bf(fmaxf(acc[fm][fn][2] * ss[2] + tt[2], 0.f));
      o.w = (short)f2bf(fmaxf(acc[fm][fn][3] * ss[3] + tt[3], 0.f));
      *(short4*)(plane + w * 256 + ((co_l * 2) ^ (((w + 1) & 7) << 4))) = o;
    }
  }
}

// ---------------- up conv: BN+ReLU then fused row-max over W ----------------
__global__ __launch_bounds__(256, 3) void conv_up_kernel(const char* __restrict__ xb,
                                                         const char* __restrict__ wp,
                                                         const float* __restrict__ st,
                                                         float* __restrict__ rmax) {
  __shared__ __align__(16) char lds[49664];
  int swz = (blockIdx.x & 7) * 64 + (blockIdx.x >> 3);
  int b = swz >> 7, h = swz & 127;
  int cohalf = blockIdx.y;
  f32x4 acc[4][4];
  zero_acc(acc);
  conv_pipeline(xb + (size_t)b * 8388608, nullptr, wp + (size_t)cohalf * 589824, nullptr,
                h, 72, lds, acc);

  const int t = threadIdx.x, lane = t & 63, wv = t >> 6;
  const int lane15 = lane & 15, q = lane >> 4, coq = wv >> 1, wh = wv & 1;
  float* rlds = (float*)lds;
  __syncthreads();
#pragma unroll
  for (int fm = 0; fm < 4; ++fm) {
    int co_l = coq * 64 + fm * 16 + q * 4;
    int co = cohalf * 128 + co_l;
#pragma unroll
    for (int r = 0; r < 4; ++r) {
      float ss = st[co + r], tt = st[256 + co + r];
      float v = 0.f;   // ReLU floor
#pragma unroll
      for (int fn = 0; fn < 4; ++fn) v = fmaxf(v, acc[fm][fn][r] * ss + tt);
      v = fmaxf(v, __shfl_xor(v, 1));
      v = fmaxf(v, __shfl_xor(v, 2));
      v = fmaxf(v, __shfl_xor(v, 4));
      v = fmaxf(v, __shfl_xor(v, 8));
      if (lane15 == 0) rlds[wh * 128 + co_l + r] = v;
    }
  }
  __syncthreads();
  if (t < 128)
    rmax[(size_t)(b * 128 + h) * 256 + cohalf * 128 + t] = fmaxf(rlds[t], rlds[128 + t]);
}

// ---------------- down conv ----------------
__global__ __launch_bounds__(256, 3) void conv_down_kernel(const char* __restrict__ xb,
                                                           const char* __restrict__ wp,
                                                           const float* __restrict__ st,
                                                           char* __restrict__ out) {
  __shared__ __align__(16) char lds[49664];
  int swz = (blockIdx.x & 7) * 64 + (blockIdx.x >> 3);
  int b = swz >> 7, h = swz & 127;
  int cohalf = blockIdx.y;
  f32x4 acc[4][4];
  zero_acc(acc);
  conv_pipeline(xb + (size_t)b * 8388608, nullptr, wp + (size_t)cohalf * 589824, nullptr,
                h, 72, lds, acc);
  store_pad_relu(acc, st, cohalf, b, h, out);
}

// ---------------- col max over H ----------------
__global__ __launch_bounds__(256) void colmax_kernel(const char* __restrict__ dp,
                                                     float* __restrict__ cmax) {
  int bw = blockIdx.x; int b = bw >> 7, w = bw & 127;
  int c = threadIdx.x;
  size_t base = (size_t)b * 8388608 + (size_t)(c >> 7) * 32768 + w * 256 +
                (((c & 127) * 2) ^ (((w + 1) & 7) << 4));
  float m = 0.f;
  for (int h = 0; h < 128; ++h) {
    u16 raw = *(const u16*)(dp + base + (size_t)h * 65536);
    m = fmaxf(m, __uint_as_float(((unsigned)raw) << 16));
  }
  cmax[(size_t)(b * 128 + w) * 256 + c] = m;
}

// ---------------- pooled = rmax[b,h,c] + cmax[b,w,c], into staging layout ----------------
__global__ __launch_bounds__(256) void pooled_kernel(const float* __restrict__ rmax,
                                                     const float* __restrict__ cmax,
                                                     char* __restrict__ dp) {
  int bh = blockIdx.x; int b = bh >> 7, h = bh & 127;
  int c = threadIdx.x;
  float rm = rmax[(size_t)(b * 128 + h) * 256 + c];
  char* plane = dp + (size_t)(b * 128 + h) * 65536 + (c >> 7) * 32768;
  int cb = (c & 127) * 2;
  for (int w = 0; w < 128; ++w) {
    float v = rm + cmax[(size_t)(b * 128 + w) * 256 + c];
    *(u16*)(plane + w * 256 + (cb ^ (((w + 1) & 7) << 4))) = f2bf(v);
  }
}

// ---------------- merge conv (pooled 3x3) + fused c1 (1x1 on xb) ----------------
__global__ __launch_bounds__(256, 3) void conv_merge_kernel(const char* __restrict__ dp,
                                                            const char* __restrict__ xb,
                                                            const char* __restrict__ wp_p,
                                                            const char* __restrict__ wp_c1,
                                                            const float* __restrict__ st,
                                                            char* __restrict__ out) {
  __shared__ __align__(16) char lds[49664];
  int swz = (blockIdx.x & 7) * 64 + (blockIdx.x >> 3);
  int b = swz >> 7, h = swz & 127;
  int cohalf = blockIdx.y;
  f32x4 acc[4][4];
  zero_acc(acc);
  conv_pipeline(dp + (size_t)b * 8388608, xb + (size_t)b * 8388608,
                wp_p + (size_t)cohalf * 589824, wp_c1 + (size_t)cohalf * 65536,
                h, 80, lds, acc);
  store_pad_relu(acc, st, cohalf, b, h, out);
}

// ---------------- final conv c2: BN+ReLU, NCHW fp32 out via LDS transpose ----------------
__global__ __launch_bounds__(256, 3) void conv_c2_kernel(const char* __restrict__ relu1,
                                                         const char* __restrict__ wp,
                                                         const float* __restrict__ st,
                                                         float* __restrict__ out) {
  __shared__ __align__(16) char lds[49664];
  int swz = (blockIdx.x & 7) * 64 + (blockIdx.x >> 3);
  int b = swz >> 7, h = swz & 127;
  int cohalf = blockIdx.y;
  f32x4 acc[4][4];
  zero_acc(acc);
  conv_pipeline(relu1 + (size_t)b * 8388608, nullptr, wp + (size_t)cohalf * 589824, nullptr,
                h, 72, lds, acc);

  const int t = threadIdx.x, lane = t & 63, wv = t >> 6;
  const int lane15 = lane & 15, q = lane >> 4, coq = wv >> 1, wh = wv & 1;
  float* tl = (float*)lds;   // [16][132]
  for (int g = 0; g < 8; ++g) {
    __syncthreads();
    if (coq == (g >> 2)) {
      int fm = g & 3;
      int co_l = coq * 64 + fm * 16 + q * 4;
      int co = cohalf * 128 + co_l;
#pragma unroll
      for (int r = 0; r < 4; ++r) {
        float ss = st[co + r], tt = st[256 + co + r];
#pragma unroll
        for (int fn = 0; fn < 4; ++fn) {
          int w = wh * 64 + fn * 16 + lane15;
          tl[(q * 4 + r) * 132 + w] = fmaxf(acc[fm][fn][r] * ss + tt, 0.f);
        }
      }
    }
    __syncthreads();
    int row = t >> 4, ch = t & 15;
    int co = cohalf * 128 + g * 16 + row;
    float* dst = out + (size_t)((b * 256 + co) * 128 + h) * 128 + ch * 8;
    float4 p0 = *(float4*)&tl[row * 132 + ch * 8];
    float4 p1 = *(float4*)&tl[row * 132 + ch * 8 + 4];
    *(float4*)dst = p0;
    *(float4*)(dst + 4) = p1;
  }
}

extern "C" void kernel_launch(void* const* d_in, const int* in_sizes, int n_in,
                              void* d_out, int out_size, void* d_ws, size_t ws_size,
                              hipStream_t stream) {
  (void)in_sizes; (void)n_in; (void)out_size; (void)ws_size;
  const float* x    = (const float*)d_in[0];
  const float* w_up = (const float*)d_in[1];
  const float* w_dn = (const float*)d_in[6];
  const float* w_p  = (const float*)d_in[11];
  const float* w_c1 = (const float*)d_in[16];
  const float* w_c2 = (const float*)d_in[21];

  // ws layout (bytes) — total 106,571,776
  char* ws = (char*)d_ws;
  char* xb    = ws;                         // 33,554,432 (32MB staging layout)
  char* dp    = ws + 33554432ull;           // 33,554,432 (down, then pooled)
  char* relu1 = ws + 67108864ull;           // 33,554,432
  u16* wp_up  = (u16*)(ws + 100663296ull);  // 1,179,648
  u16* wp_dn  = (u16*)(ws + 101842944ull);  // 1,179,648
  u16* wp_p   = (u16*)(ws + 103022592ull);  // 1,179,648
  u16* wp_c2  = (u16*)(ws + 104202240ull);  // 1,179,648
  u16* wp_c1  = (u16*)(ws + 105381888ull);  // 131,072
  float* st   = (float*)(ws + 105512960ull);// 10,240
  float* rmax = (float*)(ws + 105523200ull);// 524,288
  float* cmax = (float*)(ws + 106047488ull);// 524,288

  bn_prep_kernel<<<1, 256, 0, stream>>>((const float*)d_in[2], (const float*)d_in[3],
                                        (const float*)d_in[4], (const float*)d_in[5], st);
  bn_prep_kernel<<<1, 256, 0, stream>>>((const float*)d_in[7], (const float*)d_in[8],
                                        (const float*)d_in[9], (const float*)d_in[10], st + 512);
  bn_prep_kernel<<<1, 256, 0, stream>>>((const float*)d_in[12], (const float*)d_in[13],
                                        (const float*)d_in[14], (const float*)d_in[15], st + 1024);
  bn_prep_kernel<<<1, 256, 0, stream>>>((const float*)d_in[17], (const float*)d_in[18],
                                        (const float*)d_in[19], (const float*)d_in[20], st + 1536);
  bn_prep_kernel<<<1, 256, 0, stream>>>((const float*)d_in[22], (const float*)d_in[23],
                                        (const float*)d_in[24], (const float*)d_in[25], st + 2048);
  bn_fix_kernel<<<1, 256, 0, stream>>>(st);

  wprep3_kernel<<<2304, 256, 0, stream>>>(w_up, wp_up);
  wprep3_kernel<<<2304, 256, 0, stream>>>(w_dn, wp_dn);
  wprep3_kernel<<<2304, 256, 0, stream>>>(w_p, wp_p);
  wprep3_kernel<<<2304, 256, 0, stream>>>(w_c2, wp_c2);
  wprep1_kernel<<<256, 256, 0, stream>>>(w_c1, wp_c1, st + 1536);

  nchw_to_nhwc_kernel<<<512, 256, 0, stream>>>(x, xb);

  conv_up_kernel<<<dim3(512, 2), 256, 0, stream>>>(xb, (const char*)wp_up, st, rmax);
  conv_down_kernel<<<dim3(512, 2), 256, 0, stream>>>(xb, (const char*)wp_dn, st + 512, dp);
  colmax_kernel<<<512, 256, 0, stream>>>(dp, cmax);
  pooled_kernel<<<512, 256, 0, stream>>>(rmax, cmax, dp);
  conv_merge_kernel<<<dim3(512, 2), 256, 0, stream>>>(dp, xb, (const char*)wp_p,
                                                      (const char*)wp_c1, st + 1024, relu1);
  conv_c2_kernel<<<dim3(512, 2), 256, 0, stream>>>(relu1, (const char*)wp_c2, st + 2048,
                                                   (float*)d_out);
}